// Round 3
// baseline (669.188 us; speedup 1.0000x reference)
//
#include <hip/hip_runtime.h>

typedef __bf16 bf16x8 __attribute__((ext_vector_type(8)));
typedef __bf16 bf16x4 __attribute__((ext_vector_type(4)));
typedef short  short4v __attribute__((ext_vector_type(4)));
typedef float  f32x4  __attribute__((ext_vector_type(4)));

#define NTOK  49
#define CDIM  128
#define QK_SCALE 0.17677669529663687f   // 1/sqrt(32)

#define XS 136   // lds_x [64][136]: x bf16 (phase 0/1), then O bf16 (phase 3/4)
#define VS 72    // lds_vt [128][72]: v transposed [h*32+d][tok]

// workspace offsets (bytes)
#define WQKV_OFF  0          // 384*128 bf16 = 98304 B
#define WPROJ_OFF 98304      // 128*128 bf16 = 32768 B
#define BM_OFF    131072     // bm bf16 [64][4][64][64] = 2097152 B (bias+mask, transposed, padded)

#define MFMA32(A,B,C) __builtin_amdgcn_mfma_f32_16x16x32_bf16(A,B,C,0,0,0)
#define MFMA16(A,B,C) __builtin_amdgcn_mfma_f32_16x16x16bf16_1k(A,B,C,0,0,0)

__global__ void prep_kernel(const float* __restrict__ qkv_w,
                            const float* __restrict__ proj_w,
                            const float* __restrict__ bias_table,
                            const int*   __restrict__ rel_index,
                            const float* __restrict__ mask,
                            __bf16* __restrict__ wqkv,
                            __bf16* __restrict__ wproj,
                            __bf16* __restrict__ bm) {
    int t = blockIdx.x * 256 + threadIdx.x;   // grid covers 1048576 threads
    if (t < 384 * 128) wqkv[t]  = (__bf16)qkv_w[t];
    if (t < 128 * 128) wproj[t] = (__bf16)proj_w[t];
    // bm[wq][h][j][i]: logical bias[h][i][j] + mask[wq][i][j], stored j-major,
    // padded to 64x64 with -1e30 at j>=49 (softmax mask baked in), 0 at i>=49.
    {
        int i  = t & 63;
        int j  = (t >> 6) & 63;
        int h  = (t >> 12) & 3;
        int wq = t >> 14;
        float v;
        if (j >= NTOK)      v = -1e30f;
        else if (i >= NTOK) v = 0.0f;
        else v = bias_table[rel_index[i * 49 + j] * 4 + h] + mask[wq * 2401 + i * 49 + j];
        bm[t] = (__bf16)v;
    }
}

static __device__ __forceinline__ short4v cvt_scale(f32x4 v, float b, float sc) {
    bf16x4 r;
    #pragma unroll
    for (int i = 0; i < 4; ++i) r[i] = (__bf16)((v[i] + b) * sc);
    return __builtin_bit_cast(short4v, r);
}

__launch_bounds__(256, 4)
__global__ void winattn_kernel(const float* __restrict__ x,
                               const float* __restrict__ qkv_b,
                               const float* __restrict__ proj_b,
                               const __bf16* __restrict__ wqkv,
                               const __bf16* __restrict__ wproj,
                               const __bf16* __restrict__ bm,
                               float* __restrict__ out) {
    __shared__ __bf16 lds_x[64 * XS];
    __shared__ __bf16 lds_vt[128 * VS];

    const int tid  = threadIdx.x;
    const int w    = blockIdx.x;
    const int h    = tid >> 6;        // wave == head
    const int lane = tid & 63;
    const int quad = lane >> 4;
    const int l16  = lane & 15;

    // ---- phase 0: x fp32 -> lds_x bf16, rows >=49 zeroed --------------------
    {
        int row = tid >> 2;
        int c0  = (tid & 3) * 32;
        __align__(16) __bf16 tmp[32];
        if (row < NTOK) {
            const float4* src = (const float4*)(x + ((size_t)w * NTOK + row) * CDIM + c0);
            #pragma unroll
            for (int i = 0; i < 8; ++i) {
                float4 f = src[i];
                tmp[i*4+0] = (__bf16)f.x; tmp[i*4+1] = (__bf16)f.y;
                tmp[i*4+2] = (__bf16)f.z; tmp[i*4+3] = (__bf16)f.w;
            }
        } else {
            #pragma unroll
            for (int i = 0; i < 32; ++i) tmp[i] = (__bf16)0.0f;
        }
        bf16x8* dst = (bf16x8*)&lds_x[row * XS + c0];
        #pragma unroll
        for (int i = 0; i < 4; ++i) dst[i] = *(bf16x8*)&tmp[i*8];
    }
    __syncthreads();

    // ---- phase 1: qkv^T = Wqkv . x^T, head-local; q/k stay in registers -----
    // C-layout per tile: col = token (l16), row = feature (quad*4+r)
    short4v qf[2][4], kf[2][4];      // [d-tile kt][token-tile], 16x16x16 operand frags

    #pragma unroll
    for (int sub = 0; sub < 3; ++sub) {          // 0:q 1:k 2:v
        const int obase = sub * 128 + h * 32;
        f32x4 acc[2][4];
        #pragma unroll
        for (int a = 0; a < 2; ++a)
            #pragma unroll
            for (int b = 0; b < 4; ++b) acc[a][b] = (f32x4){0.f,0.f,0.f,0.f};

        #pragma unroll
        for (int kt = 0; kt < 4; ++kt) {
            bf16x8 aw[2];
            #pragma unroll
            for (int mt = 0; mt < 2; ++mt)
                aw[mt] = *(const bf16x8*)(wqkv + (size_t)(obase + mt*16 + l16) * CDIM + kt*32 + quad*8);
            #pragma unroll
            for (int nt = 0; nt < 4; ++nt) {
                bf16x8 xb = *(bf16x8*)&lds_x[(nt*16 + l16) * XS + kt*32 + quad*8];
                #pragma unroll
                for (int mt = 0; mt < 2; ++mt)
                    acc[mt][nt] = MFMA32(aw[mt], xb, acc[mt][nt]);
            }
        }

        float bias[2][4];
        #pragma unroll
        for (int mt = 0; mt < 2; ++mt)
            #pragma unroll
            for (int r = 0; r < 4; ++r)
                bias[mt][r] = qkv_b[obase + mt*16 + quad*4 + r];

        if (sub == 0) {
            #pragma unroll
            for (int mt = 0; mt < 2; ++mt)
                #pragma unroll
                for (int nt = 0; nt < 4; ++nt) {
                    bf16x4 r4;
                    #pragma unroll
                    for (int r = 0; r < 4; ++r)
                        r4[r] = (__bf16)((acc[mt][nt][r] + bias[mt][r]) * QK_SCALE);
                    qf[mt][nt] = __builtin_bit_cast(short4v, r4);
                }
        } else if (sub == 1) {
            #pragma unroll
            for (int mt = 0; mt < 2; ++mt)
                #pragma unroll
                for (int nt = 0; nt < 4; ++nt) {
                    bf16x4 r4;
                    #pragma unroll
                    for (int r = 0; r < 4; ++r)
                        r4[r] = (__bf16)(acc[mt][nt][r] + bias[mt][r]);
                    kf[mt][nt] = __builtin_bit_cast(short4v, r4);
                }
        } else {
            // v^T -> lds_vt[d][tok]
            #pragma unroll
            for (int mt = 0; mt < 2; ++mt)
                #pragma unroll
                for (int nt = 0; nt < 4; ++nt)
                    #pragma unroll
                    for (int r = 0; r < 4; ++r)
                        lds_vt[(h*32 + mt*16 + quad*4 + r) * VS + nt*16 + l16] =
                            (__bf16)(acc[mt][nt][r] + bias[mt][r]);
        }
    }

    // ---- phase 2: S^T = k . q^T (16x16x16 from registers); softmax over j ---
    f32x4 s[4][4];    // [jt][it]; col = i (l16), row = j (quad*4+r)
    #pragma unroll
    for (int jt = 0; jt < 4; ++jt)
        #pragma unroll
        for (int it = 0; it < 4; ++it) {
            f32x4 z = (f32x4){0.f,0.f,0.f,0.f};
            z = MFMA16(kf[0][jt], qf[0][it], z);
            s[jt][it] = MFMA16(kf[1][jt], qf[1][it], z);
        }

    // bias + mask (transposed, padded, -1e30 at j>=49 baked in)
    {
        const __bf16* bmw = bm + (((size_t)(w & 63) * 4 + h) << 12);
        #pragma unroll
        for (int jt = 0; jt < 4; ++jt)
            #pragma unroll
            for (int r = 0; r < 4; ++r) {
                int j = jt*16 + quad*4 + r;
                #pragma unroll
                for (int it = 0; it < 4; ++it)
                    s[jt][it][r] += (float)bmw[j*64 + it*16 + l16];
            }
    }

    short4v pf[4][4];   // [jt][it] A-frags for PV
    #pragma unroll
    for (int it = 0; it < 4; ++it) {
        float mx = -1e30f;
        #pragma unroll
        for (int jt = 0; jt < 4; ++jt)
            #pragma unroll
            for (int r = 0; r < 4; ++r) mx = fmaxf(mx, s[jt][it][r]);
        mx = fmaxf(mx, __shfl_xor(mx, 16, 64));
        mx = fmaxf(mx, __shfl_xor(mx, 32, 64));
        float sum = 0.f;
        #pragma unroll
        for (int jt = 0; jt < 4; ++jt)
            #pragma unroll
            for (int r = 0; r < 4; ++r) {
                float e = __expf(s[jt][it][r] - mx);
                s[jt][it][r] = e;
                sum += e;
            }
        sum += __shfl_xor(sum, 16, 64);
        sum += __shfl_xor(sum, 32, 64);
        float inv = 1.0f / sum;
        #pragma unroll
        for (int jt = 0; jt < 4; ++jt) {
            bf16x4 r4;
            #pragma unroll
            for (int r = 0; r < 4; ++r) r4[r] = (__bf16)(s[jt][it][r] * inv);
            pf[jt][it] = __builtin_bit_cast(short4v, r4);
        }
    }

    __syncthreads();   // vt written (phase 1) & all lds_x reads done before O overwrites

    // ---- phase 3: O = P . V (A=pf from regs, B from lds_vt) ------------------
    {
        short4v bv[2][4];   // [nv][kt]
        #pragma unroll
        for (int nv = 0; nv < 2; ++nv)
            #pragma unroll
            for (int kt = 0; kt < 4; ++kt)
                bv[nv][kt] = __builtin_bit_cast(short4v,
                    *(bf16x4*)&lds_vt[(h*32 + nv*16 + l16) * VS + kt*16 + quad*4]);

        f32x4 oacc[4][2];
        #pragma unroll
        for (int a = 0; a < 4; ++a)
            #pragma unroll
            for (int b = 0; b < 2; ++b) oacc[a][b] = (f32x4){0.f,0.f,0.f,0.f};

        #pragma unroll
        for (int it = 0; it < 4; ++it)
            #pragma unroll
            for (int kt = 0; kt < 4; ++kt)
                #pragma unroll
                for (int nv = 0; nv < 2; ++nv)
                    oacc[it][nv] = MFMA16(pf[kt][it], bv[nv][kt], oacc[it][nv]);

        // O C-layout: col = d (l16), row = i (quad*4+r) -> lds_x[tok][c]
        #pragma unroll
        for (int it = 0; it < 4; ++it)
            #pragma unroll
            for (int nv = 0; nv < 2; ++nv)
                #pragma unroll
                for (int r = 0; r < 4; ++r)
                    lds_x[(it*16 + quad*4 + r) * XS + h*32 + nv*16 + l16] =
                        (__bf16)oacc[it][nv][r];
    }
    __syncthreads();

    // ---- phase 4: out = O . Wproj^T + b (coalesced fp32 stores) -------------
    #pragma unroll
    for (int ntl = 0; ntl < 2; ++ntl) {
        int o = (h*2 + ntl) * 16 + l16;
        f32x4 acc[4];
        #pragma unroll
        for (int a = 0; a < 4; ++a) acc[a] = (f32x4){0.f,0.f,0.f,0.f};
        #pragma unroll
        for (int kt = 0; kt < 4; ++kt) {
            bf16x8 bf = *(const bf16x8*)(wproj + (size_t)o * CDIM + kt*32 + quad*8);
            #pragma unroll
            for (int mt = 0; mt < 4; ++mt) {
                bf16x8 af = *(bf16x8*)&lds_x[(mt*16 + l16) * XS + kt*32 + quad*8];
                acc[mt] = MFMA32(af, bf, acc[mt]);
            }
        }
        float pb = proj_b[o];
        #pragma unroll
        for (int mt = 0; mt < 4; ++mt)
            #pragma unroll
            for (int r = 0; r < 4; ++r) {
                int row = mt*16 + quad*4 + r;
                if (row < NTOK)
                    out[((size_t)w * NTOK + row) * CDIM + o] = acc[mt][r] + pb;
            }
    }
}

extern "C" void kernel_launch(void* const* d_in, const int* in_sizes, int n_in,
                              void* d_out, int out_size, void* d_ws, size_t ws_size,
                              hipStream_t stream) {
    const float* x          = (const float*)d_in[0];
    const float* mask       = (const float*)d_in[1];
    const float* qkv_w      = (const float*)d_in[2];
    const float* qkv_b      = (const float*)d_in[3];
    const float* proj_w     = (const float*)d_in[4];
    const float* proj_b     = (const float*)d_in[5];
    const float* bias_table = (const float*)d_in[6];
    const int*   rel_index  = (const int*)d_in[7];

    __bf16* wqkv  = (__bf16*)((char*)d_ws + WQKV_OFF);
    __bf16* wproj = (__bf16*)((char*)d_ws + WPROJ_OFF);
    __bf16* bm    = (__bf16*)((char*)d_ws + BM_OFF);

    int nwb = in_sizes[0] / (NTOK * CDIM);   // 8192

    prep_kernel<<<4096, 256, 0, stream>>>(qkv_w, proj_w, bias_table, rel_index,
                                          mask, wqkv, wproj, bm);
    winattn_kernel<<<nwb, 256, 0, stream>>>(x, qkv_b, proj_b,
                                            wqkv, wproj, bm, (float*)d_out);
}